// Round 3
// baseline (148.413 us; speedup 1.0000x reference)
//
#include <hip/hip_runtime.h>
#include <math.h>

#define OUT 260
#define TAPS 6
#define IMG_H 2048
#define IMG_W 2048
#define ROW_F (IMG_W * 3)            // 6144 floats per image row
#define IMG_TOTAL (IMG_H * ROW_F)
#define NB 10
#define TH 0.8f
#define ROWH 6152                    // halfs per LDS row (max span 6148 + pad)
#define NTHREADS 320                 // 5 waves; q = tid < 260 computes

__device__ __forceinline__ float sincf(float x) {
    if (x == 0.0f) return 1.0f;
    float px = 3.14159265358979323846f * x;
    return __sinf(px) / px;
}

__global__ __launch_bounds__(NTHREADS) void crop_resize_fused(
    const float* __restrict__ scores,
    const float* __restrict__ boxes,
    const float* __restrict__ img,
    float* __restrict__ out)
{
    const int p   = blockIdx.x;      // output row 0..259
    const int box = blockIdx.y;      // box 0..9

    const float b0 = boxes[box * 4 + 0];
    const float b1 = boxes[box * 4 + 1];
    const float b2 = boxes[box * 4 + 2];
    const float b3 = boxes[box * 4 + 3];

    const int y0 = (int)(b0 * (float)IMG_H);
    const int x0 = (int)(b1 * (float)IMG_W);
    const int y1 = (int)(b2 * (float)IMG_H);
    const int x1 = (int)(b3 * (float)IMG_W);
    const int ch = max(y1 - y0, 1);
    const int cw = max(x1 - x0, 1);

    const bool valid = (scores[0] >= TH) && (scores[box] >= TH)
                    && (b1 >= 0.0f) && (b3 <= 1.0f);
    const float vmask = valid ? 1.0f : 0.0f;

    // ---- vertical taps/weights (block-uniform) ----
    float wh[TAPS];
    int   ih[TAPS];
    {
        const float src = ((float)p + 0.5f) * ((float)ch / (float)OUT) - 0.5f;
        const int base = (int)floorf(src) - 2;
        float s = 0.0f;
        #pragma unroll
        for (int a = 0; a < TAPS; ++a) {
            const int tap = base + a;
            const float d = src - (float)tap;
            const float w = (fabsf(d) < 3.0f) ? sincf(d) * sincf(d * (1.0f / 3.0f)) : 0.0f;
            wh[a] = w; s += w;
            int t = tap; t = t < 0 ? 0 : t; t = t > ch - 1 ? ch - 1 : t;
            ih[a] = t + y0;
        }
        const float inv = 1.0f / s;
        #pragma unroll
        for (int a = 0; a < TAPS; ++a) wh[a] *= inv;
    }

    // ---- horizontal taps/weights (per thread) ----
    const int q = threadIdx.x;
    float ww[TAPS];
    int basew = 0;
    bool fast = false;
    if (q < OUT) {
        const float src = ((float)q + 0.5f) * ((float)cw / (float)OUT) - 0.5f;
        basew = (int)floorf(src) - 2;
        float s = 0.0f;
        #pragma unroll
        for (int k = 0; k < TAPS; ++k) {
            const float d = src - (float)(basew + k);
            const float w = (fabsf(d) < 3.0f) ? sincf(d) * sincf(d * (1.0f / 3.0f)) : 0.0f;
            ww[k] = w; s += w;
        }
        const float inv = 1.0f / s;
        #pragma unroll
        for (int k = 0; k < TAPS; ++k) ww[k] *= inv;
        fast = (basew >= 0) && (basew + 5 <= cw - 1);
    }

    // staged span (float indices within a row), 16B-aligned start
    const int start_f = (x0 * 3) & ~3;
    const int end_f   = (x0 + cw) * 3;
    const int n_f     = end_f - start_f;

    __shared__ _Float16 lds[3 * ROWH];

    float acc0 = 0.0f, acc1 = 0.0f, acc2 = 0.0f;

    for (int chunk = 0; chunk < 2; ++chunk) {
        if (chunk) __syncthreads();          // protect previous chunk's compute

        // ---- stage 3 rows fp32 -> fp16 into LDS ----
        #pragma unroll
        for (int r = 0; r < 3; ++r) {
            const int row = ih[3 * chunk + r];
            const size_t gb = (size_t)row * ROW_F + start_f;
            _Float16* lrow = lds + r * ROWH;
            for (int f = threadIdx.x * 4; f < n_f; f += NTHREADS * 4) {
                const size_t g = gb + (size_t)f;
                if (g + 4 <= (size_t)IMG_TOTAL) {
                    const float4 v = *(const float4*)(img + g);
                    lrow[f + 0] = (_Float16)v.x;
                    lrow[f + 1] = (_Float16)v.y;
                    lrow[f + 2] = (_Float16)v.z;
                    lrow[f + 3] = (_Float16)v.w;
                } else {
                    #pragma unroll
                    for (int i = 0; i < 4; ++i) {
                        size_t gi = g + i;
                        if (gi > (size_t)(IMG_TOTAL - 1)) gi = IMG_TOTAL - 1;
                        lrow[f + i] = (_Float16)img[gi];
                    }
                }
            }
        }
        __syncthreads();

        // ---- compute: horizontal 6-tap on 3 rows, vertical accumulate ----
        if (q < OUT) {
            #pragma unroll
            for (int r = 0; r < 3; ++r) {
                const float whr = wh[3 * chunk + r];
                const _Float16* lrow = lds + r * ROWH;
                float s0 = 0.0f, s1 = 0.0f, s2 = 0.0f;
                if (fast) {
                    const int hb = (x0 + basew) * 3 - start_f;   // >= 0
                    const int wb = hb >> 1;
                    const bool odd = (hb & 1) != 0;
                    const unsigned int* wp = (const unsigned int*)lrow;
                    float e[20];
                    #pragma unroll
                    for (int w = 0; w < 10; ++w) {
                        union { unsigned int u; _Float16 h[2]; } cv;
                        cv.u = wp[wb + w];
                        e[2 * w + 0] = (float)cv.h[0];
                        e[2 * w + 1] = (float)cv.h[1];
                    }
                    #pragma unroll
                    for (int k = 0; k < TAPS; ++k) {
                        const float p0 = odd ? e[3 * k + 1] : e[3 * k + 0];
                        const float p1 = odd ? e[3 * k + 2] : e[3 * k + 1];
                        const float p2 = odd ? e[3 * k + 3] : e[3 * k + 2];
                        s0 = fmaf(ww[k], p0, s0);
                        s1 = fmaf(ww[k], p1, s1);
                        s2 = fmaf(ww[k], p2, s2);
                    }
                } else {
                    #pragma unroll
                    for (int k = 0; k < TAPS; ++k) {
                        int t = basew + k;
                        t = t < 0 ? 0 : t;
                        t = t > cw - 1 ? cw - 1 : t;
                        const int hb = (x0 + t) * 3 - start_f;
                        s0 = fmaf(ww[k], (float)lrow[hb + 0], s0);
                        s1 = fmaf(ww[k], (float)lrow[hb + 1], s1);
                        s2 = fmaf(ww[k], (float)lrow[hb + 2], s2);
                    }
                }
                acc0 = fmaf(whr, s0, acc0);
                acc1 = fmaf(whr, s1, acc1);
                acc2 = fmaf(whr, s2, acc2);
            }
        }
    }

    if (q < OUT) {
        const size_t o = (((size_t)box * OUT + p) * OUT + q) * 3;
        out[o + 0] = acc0 * vmask;
        out[o + 1] = acc1 * vmask;
        out[o + 2] = acc2 * vmask;
    }
}

extern "C" void kernel_launch(void* const* d_in, const int* in_sizes, int n_in,
                              void* d_out, int out_size, void* d_ws, size_t ws_size,
                              hipStream_t stream) {
    const float* scores = (const float*)d_in[0];   // (100,)
    const float* boxes  = (const float*)d_in[1];   // (100,4)
    const float* img    = (const float*)d_in[2];   // (1,2048,2048,3)
    float* out = (float*)d_out;                    // (10,260,260,3)

    crop_resize_fused<<<dim3(OUT, NB), dim3(NTHREADS), 0, stream>>>(scores, boxes, img, out);
}

// Round 4
// 115.179 us; speedup vs baseline: 1.2885x; 1.2885x over previous
//
#include <hip/hip_runtime.h>
#include <math.h>

#define OUT 260
#define TAPS 6
#define IMG_H 2048
#define IMG_W 2048
#define ROW_F (IMG_W * 3)            // 6144 floats per image row
#define IMG_TOTAL (IMG_H * ROW_F)
#define NB 10
#define TH 0.8f
#define LDS_F 6152                   // max staged span in floats (full row + align pad)

__device__ __forceinline__ float sincf(float x) {
    if (x == 0.0f) return 1.0f;
    float px = 3.14159265358979323846f * x;
    return __sinf(px) / px;
}

__global__ __launch_bounds__(256) void crop_resize_vfirst(
    const float* __restrict__ scores,
    const float* __restrict__ boxes,
    const float* __restrict__ img,
    float* __restrict__ out)
{
    const int p   = blockIdx.x;      // output row 0..259
    const int box = blockIdx.y;      // box 0..9

    const float b0 = boxes[box * 4 + 0];
    const float b1 = boxes[box * 4 + 1];
    const float b2 = boxes[box * 4 + 2];
    const float b3 = boxes[box * 4 + 3];

    // JAX astype(int32): truncation (values >= 0 here)
    int y0 = (int)(b0 * (float)IMG_H);
    int x0 = (int)(b1 * (float)IMG_W);
    int y1 = (int)(b2 * (float)IMG_H);
    int x1 = (int)(b3 * (float)IMG_W);
    if (y1 > IMG_H) y1 = IMG_H;      // defensive; no-op for valid inputs
    if (x1 > IMG_W) x1 = IMG_W;
    const int ch = max(y1 - y0, 1);
    const int cw = max(x1 - x0, 1);

    const bool valid = (scores[0] >= TH) && (scores[box] >= TH)
                    && (b1 >= 0.0f) && (b3 <= 1.0f);
    const float vmask = valid ? 1.0f : 0.0f;

    // ---- vertical taps/weights (block-uniform -> scalar regs) ----
    float wh[TAPS];
    int   ih[TAPS];
    {
        const float src = ((float)p + 0.5f) * ((float)ch / (float)OUT) - 0.5f;
        const int base = (int)floorf(src) - 2;
        float s = 0.0f;
        #pragma unroll
        for (int a = 0; a < TAPS; ++a) {
            const int tap = base + a;
            const float d = src - (float)tap;
            const float w = (fabsf(d) < 3.0f) ? sincf(d) * sincf(d * (1.0f / 3.0f)) : 0.0f;
            wh[a] = w; s += w;
            int t = tap; t = t < 0 ? 0 : t; t = t > ch - 1 ? ch - 1 : t;
            ih[a] = t + y0;
        }
        const float inv = 1.0f / s;
        #pragma unroll
        for (int a = 0; a < TAPS; ++a) wh[a] *= inv;
    }

    // staged span (float indices within a row), 16B-aligned start
    const int start_f = (x0 * 3) & ~3;
    const int end_f   = (x0 + cw) * 3;          // <= ROW_F
    const int n_f     = end_f - start_f;

    __shared__ float lds[LDS_F];

    // ---- stage: load 6 rows, combine vertically in registers, 1 LDS row ----
    {
        const float* r0 = img + (size_t)ih[0] * ROW_F + start_f;
        const float* r1 = img + (size_t)ih[1] * ROW_F + start_f;
        const float* r2 = img + (size_t)ih[2] * ROW_F + start_f;
        const float* r3 = img + (size_t)ih[3] * ROW_F + start_f;
        const float* r4 = img + (size_t)ih[4] * ROW_F + start_f;
        const float* r5 = img + (size_t)ih[5] * ROW_F + start_f;

        for (int f = threadIdx.x * 4; f < n_f; f += 256 * 4) {
            const float4 v0 = *(const float4*)(r0 + f);
            const float4 v1 = *(const float4*)(r1 + f);
            const float4 v2 = *(const float4*)(r2 + f);
            const float4 v3 = *(const float4*)(r3 + f);
            const float4 v4 = *(const float4*)(r4 + f);
            const float4 v5 = *(const float4*)(r5 + f);
            float4 acc;
            acc.x = wh[0]*v0.x + wh[1]*v1.x + wh[2]*v2.x + wh[3]*v3.x + wh[4]*v4.x + wh[5]*v5.x;
            acc.y = wh[0]*v0.y + wh[1]*v1.y + wh[2]*v2.y + wh[3]*v3.y + wh[4]*v4.y + wh[5]*v5.y;
            acc.z = wh[0]*v0.z + wh[1]*v1.z + wh[2]*v2.z + wh[3]*v3.z + wh[4]*v4.z + wh[5]*v5.z;
            acc.w = wh[0]*v0.w + wh[1]*v1.w + wh[2]*v2.w + wh[3]*v3.w + wh[4]*v4.w + wh[5]*v5.w;
            *(float4*)(lds + f) = acc;
        }
    }
    __syncthreads();

    // ---- compute: horizontal 6-tap from the combined LDS row ----
    const float wscale = (float)cw / (float)OUT;
    for (int q = threadIdx.x; q < OUT; q += 256) {
        const float src = ((float)q + 0.5f) * wscale - 0.5f;
        const int basew = (int)floorf(src) - 2;
        float ww[TAPS];
        float s = 0.0f;
        #pragma unroll
        for (int k = 0; k < TAPS; ++k) {
            const float d = src - (float)(basew + k);
            const float w = (fabsf(d) < 3.0f) ? sincf(d) * sincf(d * (1.0f / 3.0f)) : 0.0f;
            ww[k] = w; s += w;
        }
        const float inv = 1.0f / s;

        float a0 = 0.0f, a1 = 0.0f, a2 = 0.0f;
        #pragma unroll
        for (int k = 0; k < TAPS; ++k) {
            int t = basew + k;
            t = t < 0 ? 0 : t;
            t = t > cw - 1 ? cw - 1 : t;
            const int hb = (x0 + t) * 3 - start_f;
            a0 = fmaf(ww[k], lds[hb + 0], a0);
            a1 = fmaf(ww[k], lds[hb + 1], a1);
            a2 = fmaf(ww[k], lds[hb + 2], a2);
        }
        const float m = vmask * inv;
        const size_t o = (((size_t)box * OUT + p) * OUT + q) * 3;
        out[o + 0] = a0 * m;
        out[o + 1] = a1 * m;
        out[o + 2] = a2 * m;
    }
}

extern "C" void kernel_launch(void* const* d_in, const int* in_sizes, int n_in,
                              void* d_out, int out_size, void* d_ws, size_t ws_size,
                              hipStream_t stream) {
    const float* scores = (const float*)d_in[0];   // (100,)
    const float* boxes  = (const float*)d_in[1];   // (100,4)
    const float* img    = (const float*)d_in[2];   // (1,2048,2048,3)
    float* out = (float*)d_out;                    // (10,260,260,3)

    crop_resize_vfirst<<<dim3(OUT, NB), dim3(256), 0, stream>>>(scores, boxes, img, out);
}

// Round 5
// 113.604 us; speedup vs baseline: 1.3064x; 1.0139x over previous
//
#include <hip/hip_runtime.h>
#include <math.h>

#define OUT 260
#define TAPS 6
#define IMG_H 2048
#define IMG_W 2048
#define ROW_F (IMG_W * 3)            // 6144 floats per image row
#define NB 10
#define TH 0.8f
#define QB 65                        // output columns per segment (4 * 65 = 260)
#define SEGS 4
#define LDSF 1600                    // floats: worst seg span ~520 px * 3 + align

__device__ __forceinline__ float sincf(float x) {
    if (x == 0.0f) return 1.0f;
    float px = 3.14159265358979323846f * x;
    return __sinf(px) / px;
}

// Table layout (per (box, idx) record, 16 dwords = 64 B):
//   f[0..5]  : normalized weights (vertical table: also * vmask)
//   f[6..7]  : pad
//   i[8..13] : horizontal: clamped absolute float index (x0+t)*3
//              vertical:   clamped absolute row index (t+y0)
//   i[14..15]: pad

__global__ __launch_bounds__(320) void tables_kernel(
    const float* __restrict__ scores, const float* __restrict__ boxes,
    float* __restrict__ htab, float* __restrict__ vtab)
{
    const int box = blockIdx.x;
    const float b0 = boxes[box * 4 + 0];
    const float b1 = boxes[box * 4 + 1];
    const float b2 = boxes[box * 4 + 2];
    const float b3 = boxes[box * 4 + 3];

    const int y0 = (int)(b0 * (float)IMG_H);
    const int x0 = (int)(b1 * (float)IMG_W);
    const int y1 = (int)(b2 * (float)IMG_H);
    const int x1 = (int)(b3 * (float)IMG_W);
    const int ch = max(y1 - y0, 1);
    const int cw = max(x1 - x0, 1);

    const bool valid = (scores[0] >= TH) && (scores[box] >= TH)
                    && (b1 >= 0.0f) && (b3 <= 1.0f);
    const float vmask = valid ? 1.0f : 0.0f;

    const int t = threadIdx.x;
    if (t >= OUT) return;

    // ---- horizontal record ----
    {
        const float src = ((float)t + 0.5f) * ((float)cw / (float)OUT) - 0.5f;
        const int base = (int)floorf(src) - 2;
        float w[TAPS]; int id[TAPS];
        float s = 0.0f;
        #pragma unroll
        for (int k = 0; k < TAPS; ++k) {
            const float d = src - (float)(base + k);
            const float wv = (fabsf(d) < 3.0f) ? sincf(d) * sincf(d * (1.0f / 3.0f)) : 0.0f;
            w[k] = wv; s += wv;
            int tt = base + k; tt = tt < 0 ? 0 : tt; tt = tt > cw - 1 ? cw - 1 : tt;
            id[k] = (x0 + tt) * 3;
        }
        const float inv = 1.0f / s;
        float* h = htab + ((size_t)(box * OUT + t) << 4);
        int*   hi = (int*)h;
        #pragma unroll
        for (int k = 0; k < TAPS; ++k) { h[k] = w[k] * inv; hi[8 + k] = id[k]; }
        h[6] = 0.0f; h[7] = 0.0f; hi[14] = 0; hi[15] = 0;
    }

    // ---- vertical record (vmask folded in) ----
    {
        const float src = ((float)t + 0.5f) * ((float)ch / (float)OUT) - 0.5f;
        const int base = (int)floorf(src) - 2;
        float w[TAPS]; int id[TAPS];
        float s = 0.0f;
        #pragma unroll
        for (int k = 0; k < TAPS; ++k) {
            const float d = src - (float)(base + k);
            const float wv = (fabsf(d) < 3.0f) ? sincf(d) * sincf(d * (1.0f / 3.0f)) : 0.0f;
            w[k] = wv; s += wv;
            int tt = base + k; tt = tt < 0 ? 0 : tt; tt = tt > ch - 1 ? ch - 1 : tt;
            id[k] = tt + y0;
        }
        const float inv = vmask / s;
        float* v = vtab + ((size_t)(box * OUT + t) << 4);
        int*   vi = (int*)v;
        #pragma unroll
        for (int k = 0; k < TAPS; ++k) { v[k] = w[k] * inv; vi[8 + k] = id[k]; }
        v[6] = 0.0f; v[7] = 0.0f; vi[14] = 0; vi[15] = 0;
    }
}

__global__ __launch_bounds__(64) void crop_resize_seg(
    const float* __restrict__ img,
    const float* __restrict__ htab,
    const float* __restrict__ vtab,
    float* __restrict__ out)
{
    const int seg = blockIdx.x;      // 0..3
    const int p   = blockIdx.y;      // 0..259
    const int box = blockIdx.z;      // 0..9
    const int q0  = seg * QB;

    // ---- vertical record (block-uniform) ----
    const float* vrec = vtab + ((size_t)(box * OUT + p) << 4);
    const int*   vi   = (const int*)vrec;
    float wh[TAPS]; int rows[TAPS];
    #pragma unroll
    for (int k = 0; k < TAPS; ++k) { wh[k] = vrec[k]; rows[k] = vi[8 + k]; }

    // ---- staged span from first/last q's tap indices ----
    const int* hi_first = (const int*)(htab + ((size_t)(box * OUT + q0) << 4));
    const int* hi_last  = (const int*)(htab + ((size_t)(box * OUT + q0 + QB - 1) << 4));
    const int start_f = hi_first[8] & ~3;                 // tap0 of first q, aligned down
    const int n_f     = ((hi_last[13] + 3) - start_f + 3) & ~3;  // tap5 of last q +3, aligned up

    __shared__ float lds[LDSF];

    // ---- stage: 6 rows, vertical combine in regs, 1 fp32 LDS row ----
    {
        const float* r0 = img + (size_t)rows[0] * ROW_F + start_f;
        const float* r1 = img + (size_t)rows[1] * ROW_F + start_f;
        const float* r2 = img + (size_t)rows[2] * ROW_F + start_f;
        const float* r3 = img + (size_t)rows[3] * ROW_F + start_f;
        const float* r4 = img + (size_t)rows[4] * ROW_F + start_f;
        const float* r5 = img + (size_t)rows[5] * ROW_F + start_f;

        for (int f = threadIdx.x * 4; f < n_f; f += 64 * 4) {
            const float4 v0 = *(const float4*)(r0 + f);
            const float4 v1 = *(const float4*)(r1 + f);
            const float4 v2 = *(const float4*)(r2 + f);
            const float4 v3 = *(const float4*)(r3 + f);
            const float4 v4 = *(const float4*)(r4 + f);
            const float4 v5 = *(const float4*)(r5 + f);
            float4 acc;
            acc.x = wh[0]*v0.x + wh[1]*v1.x + wh[2]*v2.x + wh[3]*v3.x + wh[4]*v4.x + wh[5]*v5.x;
            acc.y = wh[0]*v0.y + wh[1]*v1.y + wh[2]*v2.y + wh[3]*v3.y + wh[4]*v4.y + wh[5]*v5.y;
            acc.z = wh[0]*v0.z + wh[1]*v1.z + wh[2]*v2.z + wh[3]*v3.z + wh[4]*v4.z + wh[5]*v5.z;
            acc.w = wh[0]*v0.w + wh[1]*v1.w + wh[2]*v2.w + wh[3]*v3.w + wh[4]*v4.w + wh[5]*v5.w;
            *(float4*)(lds + f) = acc;
        }
    }
    __syncthreads();

    // ---- compute: horizontal 6-tap from combined LDS row ----
    for (int qi = threadIdx.x; qi < QB; qi += 64) {
        const int q = q0 + qi;
        const float* h  = htab + ((size_t)(box * OUT + q) << 4);
        const int*   hi = (const int*)h;
        float a0 = 0.0f, a1 = 0.0f, a2 = 0.0f;
        #pragma unroll
        for (int k = 0; k < TAPS; ++k) {
            const float w  = h[k];
            const int   li = hi[8 + k] - start_f;
            a0 = fmaf(w, lds[li + 0], a0);
            a1 = fmaf(w, lds[li + 1], a1);
            a2 = fmaf(w, lds[li + 2], a2);
        }
        const size_t o = (((size_t)box * OUT + p) * OUT + q) * 3;
        out[o + 0] = a0;
        out[o + 1] = a1;
        out[o + 2] = a2;
    }
}

// ---------------- Fallback (round-4 single kernel, no workspace) ----------------
__global__ __launch_bounds__(256) void crop_resize_fallback(
    const float* __restrict__ scores, const float* __restrict__ boxes,
    const float* __restrict__ img, float* __restrict__ out)
{
    const int p = blockIdx.x, box = blockIdx.y;
    const float b0 = boxes[box*4+0], b1 = boxes[box*4+1];
    const float b2 = boxes[box*4+2], b3 = boxes[box*4+3];
    const int y0 = (int)(b0*(float)IMG_H), x0 = (int)(b1*(float)IMG_W);
    const int y1 = (int)(b2*(float)IMG_H), x1 = (int)(b3*(float)IMG_W);
    const int ch = max(y1-y0,1), cw = max(x1-x0,1);
    const bool valid = (scores[0]>=TH)&&(scores[box]>=TH)&&(b1>=0.0f)&&(b3<=1.0f);
    const float vmask = valid?1.0f:0.0f;
    float wh[TAPS]; int ih[TAPS];
    {
        const float src = ((float)p+0.5f)*((float)ch/(float)OUT)-0.5f;
        const int base = (int)floorf(src)-2;
        float s = 0.0f;
        #pragma unroll
        for (int a = 0; a < TAPS; ++a) {
            const float d = src-(float)(base+a);
            const float w = (fabsf(d)<3.0f)?sincf(d)*sincf(d*(1.0f/3.0f)):0.0f;
            wh[a]=w; s+=w;
            int t=base+a; t=t<0?0:t; t=t>ch-1?ch-1:t; ih[a]=t+y0;
        }
        const float inv = 1.0f/s;
        #pragma unroll
        for (int a = 0; a < TAPS; ++a) wh[a]*=inv;
    }
    const int start_f = (x0*3)&~3;
    const int end_f = (x0+cw)*3;
    const int n_f = end_f-start_f;
    __shared__ float lds[6152];
    {
        const float* r0 = img+(size_t)ih[0]*ROW_F+start_f;
        const float* r1 = img+(size_t)ih[1]*ROW_F+start_f;
        const float* r2 = img+(size_t)ih[2]*ROW_F+start_f;
        const float* r3 = img+(size_t)ih[3]*ROW_F+start_f;
        const float* r4 = img+(size_t)ih[4]*ROW_F+start_f;
        const float* r5 = img+(size_t)ih[5]*ROW_F+start_f;
        for (int f = threadIdx.x*4; f < n_f; f += 256*4) {
            const float4 v0=*(const float4*)(r0+f), v1=*(const float4*)(r1+f);
            const float4 v2=*(const float4*)(r2+f), v3=*(const float4*)(r3+f);
            const float4 v4=*(const float4*)(r4+f), v5=*(const float4*)(r5+f);
            float4 acc;
            acc.x=wh[0]*v0.x+wh[1]*v1.x+wh[2]*v2.x+wh[3]*v3.x+wh[4]*v4.x+wh[5]*v5.x;
            acc.y=wh[0]*v0.y+wh[1]*v1.y+wh[2]*v2.y+wh[3]*v3.y+wh[4]*v4.y+wh[5]*v5.y;
            acc.z=wh[0]*v0.z+wh[1]*v1.z+wh[2]*v2.z+wh[3]*v3.z+wh[4]*v4.z+wh[5]*v5.z;
            acc.w=wh[0]*v0.w+wh[1]*v1.w+wh[2]*v2.w+wh[3]*v3.w+wh[4]*v4.w+wh[5]*v5.w;
            *(float4*)(lds+f)=acc;
        }
    }
    __syncthreads();
    const float wscale = (float)cw/(float)OUT;
    for (int q = threadIdx.x; q < OUT; q += 256) {
        const float src = ((float)q+0.5f)*wscale-0.5f;
        const int basew = (int)floorf(src)-2;
        float ww[TAPS]; float s = 0.0f;
        #pragma unroll
        for (int k = 0; k < TAPS; ++k) {
            const float d = src-(float)(basew+k);
            const float w = (fabsf(d)<3.0f)?sincf(d)*sincf(d*(1.0f/3.0f)):0.0f;
            ww[k]=w; s+=w;
        }
        const float inv = 1.0f/s;
        float a0=0,a1=0,a2=0;
        #pragma unroll
        for (int k = 0; k < TAPS; ++k) {
            int t=basew+k; t=t<0?0:t; t=t>cw-1?cw-1:t;
            const int hb=(x0+t)*3-start_f;
            a0=fmaf(ww[k],lds[hb+0],a0);
            a1=fmaf(ww[k],lds[hb+1],a1);
            a2=fmaf(ww[k],lds[hb+2],a2);
        }
        const float m = vmask*inv;
        const size_t o = (((size_t)box*OUT+p)*OUT+q)*3;
        out[o+0]=a0*m; out[o+1]=a1*m; out[o+2]=a2*m;
    }
}

extern "C" void kernel_launch(void* const* d_in, const int* in_sizes, int n_in,
                              void* d_out, int out_size, void* d_ws, size_t ws_size,
                              hipStream_t stream) {
    const float* scores = (const float*)d_in[0];   // (100,)
    const float* boxes  = (const float*)d_in[1];   // (100,4)
    const float* img    = (const float*)d_in[2];   // (1,2048,2048,3)
    float* out = (float*)d_out;                    // (10,260,260,3)

    const size_t tab_bytes = (size_t)NB * OUT * 16 * sizeof(float);  // 166,400 B each
    if (ws_size < 2 * tab_bytes) {
        crop_resize_fallback<<<dim3(OUT, NB), dim3(256), 0, stream>>>(scores, boxes, img, out);
        return;
    }
    float* htab = (float*)d_ws;
    float* vtab = (float*)((char*)d_ws + tab_bytes);

    tables_kernel<<<dim3(NB), dim3(320), 0, stream>>>(scores, boxes, htab, vtab);
    crop_resize_seg<<<dim3(SEGS, OUT, NB), dim3(64), 0, stream>>>(img, htab, vtab, out);
}